// Round 9
// baseline (1713.926 us; speedup 1.0000x reference)
//
#include <hip/hip_runtime.h>
#include <hip/hip_bf16.h>
#include <cstdint>

// ---------------------------------------------------------------------------
// LSTM  B=64 T=512 I=512 H=512
// Phase 0: convert/transpose inputs -> bf16, W_cat^T bf16, b_cat f32,
//          U pre-swizzled into MFMA B-fragment order.
// Phase 1: x_proj GEMM bf16 MFMA, bias folded, output consumer-swizzled.
// Phase 2: persistent recurrence, 64 WGs = 4 batch-groups x 16 hidden-slices.
//          U slice in registers. h exchanged via TAGGED u64 words (hi32 = tag
//          t+1, lo32 = packed bf16 col-pair), relaxed agent atomics (data IS
//          the flag) -- R8/R11-proven MALL protocol.
//
// R17 = R11 structure + EARLY-ISSUE POLL:
//   The consumer's post-publish path was sleep(512) -> issue 16 loads ->
//   wait RT(~800) -> check: sleep and round-trip SERIALIZED (~1312cyc even
//   on success). Now the 16 poll loads are issued BEFORE the sleep
//   (sched_barrier(0) pins the order); they fly to the MALL and return
//   DURING the 512cyc sleep, so the post-sleep tag check's waitcnt is
//   ~free. Success path ~max(sleep, RT) ~= 800cyc: saves ~500cyc/step.
//   Failure path unchanged + 256cyc backoff between reload-issue and
//   re-check (stops hot-loop MALL pressure -- R12 lesson). Win-or-neutral:
//   protocol bit-identical to R11, only instruction scheduling differs.
//   Also: all nt hints REVERTED (R16: FETCH rose, +20us -- nt pushed xp out
//   of the MALL). rcp gates + split-K + selective retry kept (harmless).
// Dead ends so far: cross-L2 exchange (R10), bg-interleave (R12), RMW
//   publish (R13), nt demotion (R16).
// Column convention: c = h_unit*4 + gate   (gate: 0=i,1=f,2=o,3=c)
// ---------------------------------------------------------------------------

typedef __bf16 bf16;
typedef __bf16 bf16x8 __attribute__((ext_vector_type(8)));
typedef float floatx4 __attribute__((ext_vector_type(4)));
typedef uint64_t u64;
typedef uint32_t u32;

#define T_STEPS 512

// ws layout (bytes)
#define XP_OFF     0ull                        // bf16 [T*B*2048] swizzled = 128 MB
#define XBF_OFF    134217728ull                // bf16 [T*B][512]   = 32 MB
#define WCT_OFF    167772160ull                // bf16 [2048][512]  = 2 MB
#define USW_OFF    169869312ull                // bf16 swizzled U B-frags = 2 MB
#define BCAT_OFF   171966464ull                // f32  [2048]
#define HBUF_OFF   171974656ull                // u64 [2][4][16][256] = 256 KB

__device__ inline u32 pack_bf16x2(float a, float b) {
    union { __bf16 h[2]; u32 u; } cv;
    cv.h[0] = (__bf16)a; cv.h[1] = (__bf16)b;
    return cv.u;
}
__device__ inline float bf_lo(u32 w) { return __builtin_bit_cast(float, w << 16); }
__device__ inline float bf_hi(u32 w) { return __builtin_bit_cast(float, w & 0xffff0000u); }

// fast sigmoid / tanh via v_exp + v_rcp (~1ulp rcp; fine vs bf16 rounding)
__device__ inline float fast_sigmoid(float x) {
    return __builtin_amdgcn_rcpf(1.f + __expf(-x));
}
__device__ inline float fast_tanh(float x) {
    return 1.f - 2.f * __builtin_amdgcn_rcpf(__expf(2.f * x) + 1.f);
}

// barrier that waits only LDS (lgkmcnt(0)); global loads/stores stay in flight.
// simm16: vmcnt lo[3:0]=0xF, expcnt[6:4]=7, lgkmcnt[11:8]=0, vmcnt hi[15:14]=3
__device__ inline void lgkm_barrier() {
    __atomic_signal_fence(__ATOMIC_SEQ_CST);
    __builtin_amdgcn_s_waitcnt(0xc07f);
    __builtin_amdgcn_s_barrier();
    __atomic_signal_fence(__ATOMIC_SEQ_CST);
}

// wave-local LDS write->read fence: no s_barrier, just drain LDS ops and pin
// the scheduler (rule: compiler won't order cross-lane LDS deps on its own).
__device__ inline void wave_lds_fence() {
    __atomic_signal_fence(__ATOMIC_SEQ_CST);
    __builtin_amdgcn_s_waitcnt(0xc07f);
    __builtin_amdgcn_sched_barrier(0);
    __atomic_signal_fence(__ATOMIC_SEQ_CST);
}

// ---------------- K0a: inputs f32 [B][T][I] -> x_bf bf16 in row order (t*64+b)
__global__ void k0a_convert(const float* __restrict__ in, bf16* __restrict__ xbf) {
    int o = blockIdx.x * 256 + threadIdx.x;
    int k = o & 511;
    int r = o >> 9;
    int t = r >> 6, b = r & 63;
    xbf[o] = (bf16)in[(b * 512 + t) * 512 + k];
}

// ---------------- K0b: W_cat^T[c][k] bf16 (c = h*4+gate) and b_cat f32
__global__ void k0b_wcat(const float* __restrict__ Wi, const float* __restrict__ Wf,
                         const float* __restrict__ Wo, const float* __restrict__ Wc,
                         const float* __restrict__ bi, const float* __restrict__ bfv,
                         const float* __restrict__ bo, const float* __restrict__ bc,
                         bf16* __restrict__ wct, float* __restrict__ bcat) {
    int o = blockIdx.x * 256 + threadIdx.x;      // o = c*512 + k
    int k = o & 511;
    int c = o >> 9;
    int h = c >> 2, g = c & 3;
    const float* W = (g == 0) ? Wi : (g == 1) ? Wf : (g == 2) ? Wo : Wc;
    wct[o] = (bf16)W[k * 512 + h];
    if (o < 2048) {
        int hh = o >> 2, gg = o & 3;
        const float* bv = (gg == 0) ? bi : (gg == 1) ? bfv : (gg == 2) ? bo : bc;
        bcat[o] = bv[hh];
    }
}

// ---------------- K0c: U pre-swizzled into B-fragment order for phase 2.
__global__ void k0c_uswz(const float* __restrict__ Ui, const float* __restrict__ Uf,
                         const float* __restrict__ Uo, const float* __restrict__ Uc,
                         bf16* __restrict__ usw) {
    int o = blockIdx.x * 256 + threadIdx.x;      // [0, 1048576)
    int e  = o & 7;
    int l  = (o >> 3) & 63;
    int ks = (o >> 9) & 15;
    int nt = (o >> 13) & 1;
    int w  = (o >> 14) & 3;
    int s  = o >> 16;
    int k = ks * 32 + (l >> 4) * 8 + e;
    int col_local = (2 * w + nt) * 16 + (l & 15);
    int h = s * 32 + (col_local >> 2);
    int g = col_local & 3;
    const float* U = (g == 0) ? Ui : (g == 1) ? Uf : (g == 2) ? Uo : Uc;
    usw[o] = (bf16)U[k * 512 + h];
}

// ---------------- K1: xp = x_bf @ W_cat + b_cat, output SWIZZLED for k2.
__launch_bounds__(256, 2)
__global__ void k1_gemm(const bf16* __restrict__ xbf, const bf16* __restrict__ wct,
                        const float* __restrict__ bcat, bf16* __restrict__ xp) {
    __shared__ bf16 As[128 * 40];
    __shared__ bf16 Bs[128 * 40];
    int tid = threadIdx.x;
    int wid = tid >> 6, lane = tid & 63;
    int q = lane >> 4, m = lane & 15;
    int wr = wid >> 1, wc = wid & 1;
    int br = blockIdx.x & 255, bc = blockIdx.x >> 8;

    floatx4 acc[4][4] = {};

    for (int kk = 0; kk < 16; ++kk) {
        #pragma unroll
        for (int cc = 0; cc < 2; ++cc) {
            int ch = tid + cc * 256;
            int row = ch >> 2, part = ch & 3;
            bf16x8 va = *(const bf16x8*)&xbf[(br * 128 + row) * 512 + kk * 32 + part * 8];
            bf16x8 vb = *(const bf16x8*)&wct[(bc * 128 + row) * 512 + kk * 32 + part * 8];
            *(bf16x8*)&As[row * 40 + part * 8] = va;
            *(bf16x8*)&Bs[row * 40 + part * 8] = vb;
        }
        __syncthreads();
        bf16x8 af[4], bfr[4];
        #pragma unroll
        for (int i = 0; i < 4; ++i) {
            af[i]  = *(const bf16x8*)&As[(wr * 64 + i * 16 + m) * 40 + q * 8];
            bfr[i] = *(const bf16x8*)&Bs[(wc * 64 + i * 16 + m) * 40 + q * 8];
        }
        #pragma unroll
        for (int mt = 0; mt < 4; ++mt)
            #pragma unroll
            for (int nt = 0; nt < 4; ++nt)
                acc[mt][nt] = __builtin_amdgcn_mfma_f32_16x16x32_bf16(
                    af[mt], bfr[nt], acc[mt][nt], 0, 0, 0);
        __syncthreads();
    }
    float bias[4];
    #pragma unroll
    for (int nt = 0; nt < 4; ++nt) bias[nt] = bcat[bc * 128 + wc * 64 + nt * 16 + m];
    #pragma unroll
    for (int mt = 0; mt < 4; ++mt) {
        #pragma unroll
        for (int nt = 0; nt < 4; ++nt) {
            u32 p0 = pack_bf16x2(acc[mt][nt][0] + bias[nt], acc[mt][nt][1] + bias[nt]);
            u32 p1 = pack_bf16x2(acc[mt][nt][2] + bias[nt], acc[mt][nt][3] + bias[nt]);
            size_t idx = (((((size_t)(br * 2 + wr) * 4 + mt) * 16 + bc) * 8
                           + wc * 4 + nt) * 64 + lane) * 4;
            uint2 v; v.x = p0; v.y = p1;
            *(uint2*)&xp[idx] = v;
        }
    }
}

// ---------------- K2: persistent recurrence (R11 structure; EARLY-ISSUE
// poll; selective retry w/ backoff; rcp gates; split-K MFMA).
// hbuf: u64[2][4][16][256]; word (par,bg,row,pc): hi32 = tag t+1, lo32 =
// packed bf16 col-pair. Store parity t&1, read (t-1)&1.
__launch_bounds__(256, 1)
__global__ void k2_rec(const bf16* __restrict__ xp, const bf16* __restrict__ usw,
                       u64* __restrict__ hbuf, float* __restrict__ out) {
    // h staging: [parity][row][256 words], rows stride 512 bf16 (1024B), 16B
    // chunks XOR-swizzled by (row&7). 32 KB total.
    __shared__ u32 h_sh[2][16 * 256];
    // per-wave gate slab: [wave][16 rows][36 floats] (stride 36 -> 2-way writes)
    __shared__ float g_slab[4][16 * 36];

    int tid = threadIdx.x;
    int wid = tid >> 6, lane = tid & 63;
    int q = lane >> 4, m = lane & 15;
    int bg = blockIdx.x & 3, s = blockIdx.x >> 2;

    // U B-fragments in registers (one-time, reused all 512 steps)
    bf16x8 bfr[2][16];
    {
        const bf16x8* base = (const bf16x8*)usw;
        #pragma unroll
        for (int nt = 0; nt < 2; ++nt)
            #pragma unroll
            for (int ks = 0; ks < 16; ++ks)
                bfr[nt][ks] = base[(((s * 4 + wid) * 2 + nt) * 16 + ks) * 64 + lane];
    }

    // wave-local gate/publish identity: lane -> (row r2, unit pair kk2).
    int r2 = lane >> 2;                            // 0..15
    int kk2 = lane & 3;                            // 0..3
    float cs0 = 0.f, cs1 = 0.f;

    // h_sh write swizzle constants: write i -> word i*256+((wc^(i&7))<<2)+wk
    int wc = tid >> 2, wk = tid & 3;

    float* gs = &g_slab[wid][0];

    // prefetch xp for t=0
    uint2 vx0, vx1;
    {
        size_t b0 = ((((size_t)bg * 16 + s) * 8 + wid * 2) * 64 + lane) * 4;
        vx0 = *(const uint2*)&xp[b0];
        vx1 = *(const uint2*)&xp[b0 + 256];
    }

    for (int t = 0; t < T_STEPS; ++t) {
        floatx4 acc[2];

        // unpack the xp prefetch (issued last step; retired by now)
        acc[0][0] = bf_lo(vx0.x); acc[0][1] = bf_hi(vx0.x);
        acc[0][2] = bf_lo(vx0.y); acc[0][3] = bf_hi(vx0.y);
        acc[1][0] = bf_lo(vx1.x); acc[1][1] = bf_hi(vx1.x);
        acc[1][2] = bf_lo(vx1.y); acc[1][3] = bf_hi(vx1.y);

        if (t > 0) {
            const u64* rb = hbuf + ((size_t)((t - 1) & 1) * 4 + bg) * 4096;
            u32 tg = (u32)t;
            u64 w[16];

            // EARLY-ISSUE: launch all 16 poll loads BEFORE the calibrated
            // sleep; they round-trip to the MALL while we sleep, so the
            // post-sleep tag check's waitcnt is ~free on the success path.
            #pragma unroll
            for (int i = 0; i < 16; ++i)
                w[i] = __hip_atomic_load(rb + tid + 256 * i, __ATOMIC_RELAXED,
                                         __HIP_MEMORY_SCOPE_AGENT);
            __builtin_amdgcn_sched_barrier(0);    // pin issue order vs sleep
            __builtin_amdgcn_s_sleep(8);          // ~512 cyc visibility window
            __atomic_signal_fence(__ATOMIC_SEQ_CST);

            for (;;) {
                bool ok = true;
                #pragma unroll
                for (int i = 0; i < 16; ++i) ok &= ((u32)(w[i] >> 32) == tg);
                if (ok) break;
                // selective reload of stale words; backoff between issue and
                // re-check so retries don't hammer the MALL (R12 lesson) and
                // the reloads land during the backoff sleep.
                #pragma unroll
                for (int i = 0; i < 16; ++i)
                    if ((u32)(w[i] >> 32) != tg)
                        w[i] = __hip_atomic_load(rb + tid + 256 * i, __ATOMIC_RELAXED,
                                                 __HIP_MEMORY_SCOPE_AGENT);
                __builtin_amdgcn_sched_barrier(0);
                __builtin_amdgcn_s_sleep(4);      // ~256 cyc backoff
                __atomic_signal_fence(__ATOMIC_SEQ_CST);
            }
            // stage h into parity buffer (t-1)&1 with XOR-swizzled chunks
            u32* hp = &h_sh[(t & 1) ^ 1][0];
            #pragma unroll
            for (int i = 0; i < 16; ++i)
                hp[i * 256 + ((wc ^ (i & 7)) << 2) + wk] = (u32)w[i];
            lgkm_barrier();                       // the ONLY barrier per step
            const bf16* hbs = (const bf16*)hp;
            // split-K: two independent 8-deep chains per n-tile
            floatx4 accb0 = {}, accb1 = {};
            #pragma unroll
            for (int ks = 0; ks < 8; ++ks) {
                bf16x8 af = *(const bf16x8*)&hbs[m * 512 + (((4 * ks + q) ^ (m & 7)) << 3)];
                acc[0] = __builtin_amdgcn_mfma_f32_16x16x32_bf16(af, bfr[0][ks], acc[0], 0, 0, 0);
                acc[1] = __builtin_amdgcn_mfma_f32_16x16x32_bf16(af, bfr[1][ks], acc[1], 0, 0, 0);
            }
            #pragma unroll
            for (int ks = 8; ks < 16; ++ks) {
                bf16x8 af = *(const bf16x8*)&hbs[m * 512 + (((4 * ks + q) ^ (m & 7)) << 3)];
                accb0 = __builtin_amdgcn_mfma_f32_16x16x32_bf16(af, bfr[0][ks], accb0, 0, 0, 0);
                accb1 = __builtin_amdgcn_mfma_f32_16x16x32_bf16(af, bfr[1][ks], accb1, 0, 0, 0);
            }
            acc[0] += accb0;
            acc[1] += accb1;
        }

        // prefetch next step's xp NOW; survives the lgkm-only barrier and
        // retires off the critical path.
        if (t + 1 < T_STEPS) {
            size_t b0 = (((((size_t)(t + 1) * 4 + bg) * 16 + s) * 8 + wid * 2) * 64 + lane) * 4;
            vx0 = *(const uint2*)&xp[b0];
            vx1 = *(const uint2*)&xp[b0 + 256];
        }

        // wave-private gate staging: lane (m,q) holds (row q*4+rr, col nt*16+m)
        #pragma unroll
        for (int nt = 0; nt < 2; ++nt)
            #pragma unroll
            for (int rr = 0; rr < 4; ++rr)
                gs[(q * 4 + rr) * 36 + nt * 16 + m] = acc[nt][rr];
        wave_lds_fence();                          // no s_barrier needed

        // gates: lane (r2, units wid*8+2*kk2, +1) -- two aligned b128 reads
        floatx4 ga = *(const floatx4*)&gs[r2 * 36 + kk2 * 8];
        floatx4 gb = *(const floatx4*)&gs[r2 * 36 + kk2 * 8 + 4];
        float h0, h1;
        {
            float ig = fast_sigmoid(ga[0]);
            float fg = fast_sigmoid(ga[1]);
            float og = fast_sigmoid(ga[2]);
            float th = fast_tanh(ga[3]);
            cs0 = fg * cs0 + ig * th;
            h0 = og * fast_tanh(cs0);
        }
        {
            float ig = fast_sigmoid(gb[0]);
            float fg = fast_sigmoid(gb[1]);
            float og = fast_sigmoid(gb[2]);
            float th = fast_tanh(gb[3]);
            cs1 = fg * cs1 + ig * th;
            h1 = og * fast_tanh(cs1);
        }
        // per-wave tagged publish, fire-and-forget (plain agent store)
        u64 word = ((u64)(u32)(t + 1) << 32) | (u64)pack_bf16x2(h0, h1);
        __hip_atomic_store(hbuf + (((size_t)(t & 1) * 4 + bg) * 16 + r2) * 256
                                + s * 16 + wid * 4 + kk2,
                           word, __ATOMIC_RELAXED, __HIP_MEMORY_SCOPE_AGENT);
        if (t == T_STEPS - 1) {
            int u0 = s * 32 + wid * 8 + kk2 * 2;
            out[(bg * 16 + r2) * 512 + u0]     = h0;
            out[(bg * 16 + r2) * 512 + u0 + 1] = h1;
        }
    }
}

// ---------------------------------------------------------------------------
extern "C" void kernel_launch(void* const* d_in, const int* in_sizes, int n_in,
                              void* d_out, int out_size, void* d_ws, size_t ws_size,
                              hipStream_t stream) {
    const float* inp = (const float*)d_in[0];
    const float* Wi  = (const float*)d_in[1];
    const float* Wf  = (const float*)d_in[2];
    const float* Wo  = (const float*)d_in[3];
    const float* Wc  = (const float*)d_in[4];
    const float* Ui  = (const float*)d_in[5];
    const float* Uf  = (const float*)d_in[6];
    const float* Uo  = (const float*)d_in[7];
    const float* Uc  = (const float*)d_in[8];
    const float* bi  = (const float*)d_in[9];
    const float* bfv = (const float*)d_in[10];
    const float* bo  = (const float*)d_in[11];
    const float* bc  = (const float*)d_in[12];

    char* ws = (char*)d_ws;
    bf16*  xp    = (bf16*)(ws + XP_OFF);
    bf16*  xbf   = (bf16*)(ws + XBF_OFF);
    bf16*  wct   = (bf16*)(ws + WCT_OFF);
    bf16*  usw   = (bf16*)(ws + USW_OFF);
    float* bcat  = (float*)(ws + BCAT_OFF);
    u64*   hbuf  = (u64*)(ws + HBUF_OFF);

    k0a_convert<<<65536, 256, 0, stream>>>(inp, xbf);
    k0b_wcat<<<4096, 256, 0, stream>>>(Wi, Wf, Wo, Wc, bi, bfv, bo, bc, wct, bcat);
    k0c_uswz<<<4096, 256, 0, stream>>>(Ui, Uf, Uo, Uc, usw);
    k1_gemm<<<4096, 256, 0, stream>>>(xbf, wct, bcat, xp);
    k2_rec<<<64, 256, 0, stream>>>(xp, usw, hbuf, (float*)d_out);
}